// Round 1
// baseline (801.466 us; speedup 1.0000x reference)
//
#include <hip/hip_runtime.h>

#define DEV __device__ __forceinline__

typedef __attribute__((ext_vector_type(8))) short bf16x8;
typedef __attribute__((ext_vector_type(4))) float f32x4;

constexpr int B = 4, S = 2048, D = 1024, H = 16, DK = 64, DFF = 4096;
constexpr int NT = B * S;  // 8192 tokens

DEV unsigned short f2bf(float f) {
  unsigned u = __float_as_uint(f);
  u += 0x7fff + ((u >> 16) & 1);   // round-to-nearest-even
  return (unsigned short)(u >> 16);
}

// ---------------- fp32 -> bf16 elementwise ----------------
__global__ __launch_bounds__(256) void cvt_bf16_kernel(const float* __restrict__ in,
                                                       unsigned short* __restrict__ out, int n) {
  int i = (blockIdx.x * 256 + threadIdx.x) * 8;
  if (i >= n) return;
  float4 a = *(const float4*)(in + i);
  float4 b = *(const float4*)(in + i + 4);
  uint4 o;
  o.x = f2bf(a.x) | ((unsigned)f2bf(a.y) << 16);
  o.y = f2bf(a.z) | ((unsigned)f2bf(a.w) << 16);
  o.z = f2bf(b.x) | ((unsigned)f2bf(b.y) << 16);
  o.w = f2bf(b.z) | ((unsigned)f2bf(b.w) << 16);
  *(uint4*)(out + i) = o;
}

// ---------------- fp32 (R x C) -> bf16 transposed (C x R) ----------------
__global__ __launch_bounds__(256) void transpose_cvt_kernel(const float* __restrict__ in,
                                                            unsigned short* __restrict__ out,
                                                            int R, int C) {
  __shared__ unsigned short tile[64][72];
  int rb = blockIdx.y * 64, cb = blockIdx.x * 64;
  int t = threadIdx.x;
#pragma unroll
  for (int i = 0; i < 16; ++i) {
    int c = t + i * 256;
    int r = c >> 6, cc = c & 63;
    tile[cc][r] = f2bf(in[(size_t)(rb + r) * C + cb + cc]);
  }
  __syncthreads();
#pragma unroll
  for (int i = 0; i < 16; ++i) {
    int c = t + i * 256;
    int rr = c >> 6, cc = c & 63;
    out[(size_t)(cb + rr) * R + rb + cc] = tile[rr][cc];
  }
}

// ---------------- GEMM: out = act(A @ W + bias) ----------------
// A: M x K bf16 row-major.  WT: N x K bf16 (weight transposed).  bias: fp32.
// 128x128 tile, BK=32, 4 waves each 64x64. LDS rows padded to 48 elems (96B) for
// aligned ds_read_b128 + reduced bank conflicts.
template <bool RELU, bool OUT_BF16>
__global__ __launch_bounds__(256) void gemm_kernel(const unsigned short* __restrict__ A,
                                                   const unsigned short* __restrict__ WT,
                                                   const float* __restrict__ bias,
                                                   void* __restrict__ out,
                                                   int M, int N, int K) {
  __shared__ __align__(16) unsigned short sA[128 * 48];
  __shared__ __align__(16) unsigned short sB[128 * 48];
  int t = threadIdx.x;
  int w = t >> 6, l = t & 63;
  int ll = l & 15, lh = l >> 4;
  int bn = blockIdx.x, bm = blockIdx.y;
  int wm = (w & 1) * 64, wn = (w >> 1) * 64;

  f32x4 acc[4][4] = {};
  const size_t arow0 = (size_t)bm * 128;
  const size_t brow0 = (size_t)bn * 128;

  for (int kb = 0; kb < K; kb += 32) {
    __syncthreads();
#pragma unroll
    for (int i = 0; i < 2; ++i) {
      int c = t + i * 256;
      int r = c >> 2, cb8 = (c & 3) * 8;
      uint4 va = *(const uint4*)(A + (arow0 + r) * K + kb + cb8);
      *(uint4*)(sA + r * 48 + cb8) = va;
      uint4 vb = *(const uint4*)(WT + (brow0 + r) * K + kb + cb8);
      *(uint4*)(sB + r * 48 + cb8) = vb;
    }
    __syncthreads();
    bf16x8 af[4], bfr[4];
#pragma unroll
    for (int mt = 0; mt < 4; ++mt)
      af[mt] = *(const bf16x8*)(sA + (wm + mt * 16 + ll) * 48 + lh * 8);
#pragma unroll
    for (int nt = 0; nt < 4; ++nt)
      bfr[nt] = *(const bf16x8*)(sB + (wn + nt * 16 + ll) * 48 + lh * 8);
#pragma unroll
    for (int mt = 0; mt < 4; ++mt)
#pragma unroll
      for (int nt = 0; nt < 4; ++nt)
        acc[mt][nt] = __builtin_amdgcn_mfma_f32_16x16x32_bf16(af[mt], bfr[nt], acc[mt][nt], 0, 0, 0);
  }

#pragma unroll
  for (int mt = 0; mt < 4; ++mt) {
#pragma unroll
    for (int nt = 0; nt < 4; ++nt) {
      int col = bn * 128 + wn + nt * 16 + ll;
      float bv = bias[col];
#pragma unroll
      for (int r = 0; r < 4; ++r) {
        int row = bm * 128 + wm + mt * 16 + lh * 4 + r;
        float v = acc[mt][nt][r] + bv;
        if (RELU) v = fmaxf(v, 0.f);
        if (OUT_BF16)
          ((unsigned short*)out)[(size_t)row * N + col] = f2bf(v);
        else
          ((float*)out)[(size_t)row * N + col] = v;
      }
    }
  }
}

// ---------------- Flash attention ----------------
// Block: 4 waves, each owns 16 q-rows (64 q-rows/block). Loop keys in blocks of 32.
// q,k,v,ctx: (B,S,D) bf16 with head h at cols h*64..h*64+63.
__global__ __launch_bounds__(256) void attn_kernel(const unsigned short* __restrict__ q,
                                                   const unsigned short* __restrict__ k,
                                                   const unsigned short* __restrict__ v,
                                                   unsigned short* __restrict__ ctx) {
  __shared__ __align__(16) unsigned short sVt[64 * 48];      // V-tile transposed [d][key]
  __shared__ __align__(16) unsigned short sP[4 * 16 * 48];   // per-wave P scratch
  int t = threadIdx.x, w = t >> 6, l = t & 63;
  int ll = l & 15, lh = l >> 4;
  int bh = blockIdx.y, b = bh >> 4, h = bh & 15;
  int q0 = blockIdx.x * 64 + w * 16;
  const size_t base = ((size_t)b * S) * D + (size_t)h * DK;

  bf16x8 qf[2];
#pragma unroll
  for (int kk = 0; kk < 2; ++kk)
    qf[kk] = *(const bf16x8*)(q + base + (size_t)(q0 + ll) * D + kk * 32 + lh * 8);

  f32x4 cacc[4] = {};
  float m[4], lsum[4];
#pragma unroll
  for (int r = 0; r < 4; ++r) { m[r] = -1e30f; lsum[r] = 0.f; }

  unsigned short* sPw = sP + w * 16 * 48;

  for (int kb = 0; kb < S; kb += 32) {
    {  // stage Vt
      int key = t >> 3, db = (t & 7) * 8;
      uint4 vv = *(const uint4*)(v + base + (size_t)(kb + key) * D + db);
      const unsigned short* vs = (const unsigned short*)&vv;
#pragma unroll
      for (int j = 0; j < 8; ++j) sVt[(db + j) * 48 + key] = vs[j];
    }
    __syncthreads();

    f32x4 sc[2] = {};
#pragma unroll
    for (int nt = 0; nt < 2; ++nt)
#pragma unroll
      for (int kk = 0; kk < 2; ++kk) {
        bf16x8 kf = *(const bf16x8*)(k + base + (size_t)(kb + nt * 16 + ll) * D + kk * 32 + lh * 8);
        sc[nt] = __builtin_amdgcn_mfma_f32_16x16x32_bf16(qf[kk], kf, sc[nt], 0, 0, 0);
      }

#pragma unroll
    for (int r = 0; r < 4; ++r) {
      float s0 = sc[0][r] * 0.125f, s1 = sc[1][r] * 0.125f;
      float mv = fmaxf(s0, s1);
#pragma unroll
      for (int msk = 8; msk; msk >>= 1) mv = fmaxf(mv, __shfl_xor(mv, msk));
      float mn = fmaxf(m[r], mv);
      float resc = __expf(m[r] - mn);
      float p0 = __expf(s0 - mn), p1 = __expf(s1 - mn);
      float rs = p0 + p1;
#pragma unroll
      for (int msk = 8; msk; msk >>= 1) rs += __shfl_xor(rs, msk);
      lsum[r] = lsum[r] * resc + rs;
      m[r] = mn;
#pragma unroll
      for (int dt = 0; dt < 4; ++dt) cacc[dt][r] *= resc;
      sPw[(lh * 4 + r) * 48 + ll] = f2bf(p0);
      sPw[(lh * 4 + r) * 48 + 16 + ll] = f2bf(p1);
    }
    __syncthreads();

    bf16x8 pf = *(const bf16x8*)(sPw + ll * 48 + lh * 8);
#pragma unroll
    for (int dt = 0; dt < 4; ++dt) {
      bf16x8 vf = *(const bf16x8*)(sVt + (dt * 16 + ll) * 48 + lh * 8);
      cacc[dt] = __builtin_amdgcn_mfma_f32_16x16x32_bf16(pf, vf, cacc[dt], 0, 0, 0);
    }
    __syncthreads();
  }

#pragma unroll
  for (int dt = 0; dt < 4; ++dt)
#pragma unroll
    for (int r = 0; r < 4; ++r) {
      float val = cacc[dt][r] / lsum[r];
      ctx[base + (size_t)(q0 + lh * 4 + r) * D + dt * 16 + ll] = f2bf(val);
    }
}

// ---------------- residual + LayerNorm (fp32 out + optional bf16 out) ----------------
template <bool WRITE_BF16>
__global__ __launch_bounds__(256) void add_ln_kernel(const float* __restrict__ a,
                                                     const float* __restrict__ bres,
                                                     const float* __restrict__ gamma,
                                                     const float* __restrict__ beta,
                                                     float* __restrict__ outf,
                                                     unsigned short* __restrict__ outb) {
  __shared__ float sred[8];
  size_t row = blockIdx.x;
  int t = threadIdx.x;
  size_t bidx = row * D + t * 4;
  float4 va = *(const float4*)(a + bidx);
  float4 vb = *(const float4*)(bres + bidx);
  float4 x;
  x.x = va.x + vb.x; x.y = va.y + vb.y; x.z = va.z + vb.z; x.w = va.w + vb.w;

  float s = x.x + x.y + x.z + x.w;
#pragma unroll
  for (int msk = 32; msk; msk >>= 1) s += __shfl_xor(s, msk);
  if ((t & 63) == 0) sred[t >> 6] = s;
  __syncthreads();
  float mu = (sred[0] + sred[1] + sred[2] + sred[3]) * (1.f / D);

  float dx = x.x - mu, dy = x.y - mu, dz = x.z - mu, dw = x.w - mu;
  float sq = dx * dx + dy * dy + dz * dz + dw * dw;
#pragma unroll
  for (int msk = 32; msk; msk >>= 1) sq += __shfl_xor(sq, msk);
  __syncthreads();
  if ((t & 63) == 0) sred[t >> 6] = sq;
  __syncthreads();
  float var = (sred[0] + sred[1] + sred[2] + sred[3]) * (1.f / D);
  float rs = rsqrtf(var + 1e-5f);

  float4 g = *(const float4*)(gamma + t * 4);
  float4 be = *(const float4*)(beta + t * 4);
  float4 y;
  y.x = dx * rs * g.x + be.x;
  y.y = dy * rs * g.y + be.y;
  y.z = dz * rs * g.z + be.z;
  y.w = dw * rs * g.w + be.w;
  *(float4*)(outf + bidx) = y;
  if (WRITE_BF16) {
    uint2 o;
    o.x = (unsigned)f2bf(y.x) | ((unsigned)f2bf(y.y) << 16);
    o.y = (unsigned)f2bf(y.z) | ((unsigned)f2bf(y.w) << 16);
    *(uint2*)(outb + bidx) = o;
  }
}

extern "C" void kernel_launch(void* const* d_in, const int* in_sizes, int n_in,
                              void* d_out, int out_size, void* d_ws, size_t ws_size,
                              hipStream_t stream) {
  const float* x   = (const float*)d_in[0];
  const float* wq  = (const float*)d_in[1];
  const float* bq  = (const float*)d_in[2];
  const float* wk  = (const float*)d_in[3];
  const float* bk  = (const float*)d_in[4];
  const float* wv  = (const float*)d_in[5];
  const float* bv  = (const float*)d_in[6];
  const float* wo  = (const float*)d_in[7];
  const float* bo  = (const float*)d_in[8];
  const float* w1  = (const float*)d_in[9];
  const float* b1  = (const float*)d_in[10];
  const float* w2  = (const float*)d_in[11];
  const float* b2  = (const float*)d_in[12];
  const float* g1  = (const float*)d_in[13];
  const float* be1 = (const float*)d_in[14];
  const float* g2  = (const float*)d_in[15];
  const float* be2 = (const float*)d_in[16];

  char* ws = (char*)d_ws;
  size_t off = 0;
  auto alloc = [&](size_t bytes) {
    char* p = ws + off;
    off += (bytes + 255) & ~(size_t)255;
    return p;
  };

  unsigned short* wqT = (unsigned short*)alloc((size_t)D * D * 2);
  unsigned short* wkT = (unsigned short*)alloc((size_t)D * D * 2);
  unsigned short* wvT = (unsigned short*)alloc((size_t)D * D * 2);
  unsigned short* woT = (unsigned short*)alloc((size_t)D * D * 2);
  unsigned short* w1T = (unsigned short*)alloc((size_t)D * DFF * 2);
  unsigned short* w2T = (unsigned short*)alloc((size_t)DFF * D * 2);
  unsigned short* xb  = (unsigned short*)alloc((size_t)NT * D * 2);   // reused as x1b
  unsigned short* qb  = (unsigned short*)alloc((size_t)NT * D * 2);   // q|k|v|ctx contiguous,
  unsigned short* kb_ = (unsigned short*)alloc((size_t)NT * D * 2);   // reused as ff (NT x DFF)
  unsigned short* vb_ = (unsigned short*)alloc((size_t)NT * D * 2);
  unsigned short* ctb = (unsigned short*)alloc((size_t)NT * D * 2);
  float* attn_out = (float*)alloc((size_t)NT * D * 4);                // reused as ff2
  float* x1f      = (float*)alloc((size_t)NT * D * 4);
  unsigned short* x1b = xb;
  unsigned short* ffb = qb;
  float* ff2 = attn_out;
  (void)ctb; (void)ws_size; (void)in_sizes; (void)n_in; (void)out_size;

  // 1. convert x + weights to bf16 (weights transposed)
  cvt_bf16_kernel<<<NT * D / 2048, 256, 0, stream>>>(x, xb, NT * D);
  transpose_cvt_kernel<<<dim3(D / 64, D / 64), 256, 0, stream>>>(wq, wqT, D, D);
  transpose_cvt_kernel<<<dim3(D / 64, D / 64), 256, 0, stream>>>(wk, wkT, D, D);
  transpose_cvt_kernel<<<dim3(D / 64, D / 64), 256, 0, stream>>>(wv, wvT, D, D);
  transpose_cvt_kernel<<<dim3(D / 64, D / 64), 256, 0, stream>>>(wo, woT, D, D);
  transpose_cvt_kernel<<<dim3(DFF / 64, D / 64), 256, 0, stream>>>(w1, w1T, D, DFF);
  transpose_cvt_kernel<<<dim3(D / 64, DFF / 64), 256, 0, stream>>>(w2, w2T, DFF, D);

  // 2. QKV projections
  gemm_kernel<false, true><<<dim3(D / 128, NT / 128), 256, 0, stream>>>(xb, wqT, bq, qb, NT, D, D);
  gemm_kernel<false, true><<<dim3(D / 128, NT / 128), 256, 0, stream>>>(xb, wkT, bk, kb_, NT, D, D);
  gemm_kernel<false, true><<<dim3(D / 128, NT / 128), 256, 0, stream>>>(xb, wvT, bv, vb_, NT, D, D);

  // 3. attention
  attn_kernel<<<dim3(S / 64, B * H), 256, 0, stream>>>(qb, kb_, vb_, ctb);

  // 4. output projection (fp32 out for residual)
  gemm_kernel<false, false><<<dim3(D / 128, NT / 128), 256, 0, stream>>>(ctb, woT, bo, attn_out, NT, D, D);

  // 5. x1 = LN(x + attn_out)
  add_ln_kernel<true><<<NT, 256, 0, stream>>>(x, attn_out, g1, be1, x1f, x1b);

  // 6. FF
  gemm_kernel<true, true><<<dim3(DFF / 128, NT / 128), 256, 0, stream>>>(x1b, w1T, b1, ffb, NT, DFF, D);
  gemm_kernel<false, false><<<dim3(D / 128, NT / 128), 256, 0, stream>>>(ffb, w2T, b2, ff2, NT, D, DFF);

  // 7. out = LN(x1 + ff)
  add_ln_kernel<false><<<NT, 256, 0, stream>>>(x1f, ff2, g2, be2, (float*)d_out, nullptr);
}

// Round 2
// 676.229 us; speedup vs baseline: 1.1852x; 1.1852x over previous
//
#include <hip/hip_runtime.h>

#define DEV __device__ __forceinline__

typedef __attribute__((ext_vector_type(8))) short bf16x8;
typedef __attribute__((ext_vector_type(4))) float f32x4;

constexpr int B = 4, S = 2048, D = 1024, H = 16, DK = 64, DFF = 4096;
constexpr int NT = B * S;  // 8192 tokens

DEV unsigned short f2bf(float f) {
  unsigned u = __float_as_uint(f);
  u += 0x7fff + ((u >> 16) & 1);   // round-to-nearest-even
  return (unsigned short)(u >> 16);
}

// async global->LDS 16B: lds base must be wave-uniform; each lane deposits at base+lane*16
DEV void gld16(unsigned short* ldsbase, const unsigned short* g, int lane) {
#if __has_builtin(__builtin_amdgcn_global_load_lds)
  __builtin_amdgcn_global_load_lds((const __attribute__((address_space(1))) unsigned int*)g,
                                   (__attribute__((address_space(3))) unsigned int*)ldsbase,
                                   16, 0, 0);
#else
  *(uint4*)(ldsbase + lane * 8) = *(const uint4*)g;
#endif
}

// ---------------- fp32 -> bf16 elementwise ----------------
__global__ __launch_bounds__(256) void cvt_bf16_kernel(const float* __restrict__ in,
                                                       unsigned short* __restrict__ out, int n) {
  int i = (blockIdx.x * 256 + threadIdx.x) * 8;
  if (i >= n) return;
  float4 a = *(const float4*)(in + i);
  float4 b = *(const float4*)(in + i + 4);
  uint4 o;
  o.x = f2bf(a.x) | ((unsigned)f2bf(a.y) << 16);
  o.y = f2bf(a.z) | ((unsigned)f2bf(a.w) << 16);
  o.z = f2bf(b.x) | ((unsigned)f2bf(b.y) << 16);
  o.w = f2bf(b.z) | ((unsigned)f2bf(b.w) << 16);
  *(uint4*)(out + i) = o;
}

// ---------------- fp32 (R x C) -> bf16 transposed (C x R) ----------------
__global__ __launch_bounds__(256) void transpose_cvt_kernel(const float* __restrict__ in,
                                                            unsigned short* __restrict__ out,
                                                            int R, int C) {
  __shared__ unsigned short tile[64][72];
  int rb = blockIdx.y * 64, cb = blockIdx.x * 64;
  int t = threadIdx.x;
#pragma unroll
  for (int i = 0; i < 16; ++i) {
    int c = t + i * 256;
    int r = c >> 6, cc = c & 63;
    tile[cc][r] = f2bf(in[(size_t)(rb + r) * C + cb + cc]);
  }
  __syncthreads();
#pragma unroll
  for (int i = 0; i < 16; ++i) {
    int c = t + i * 256;
    int rr = c >> 6, cc = c & 63;
    out[(size_t)(cb + rr) * R + rb + cc] = tile[rr][cc];
  }
}

// ---------------- GEMM: out = act(A @ W + bias) ----------------
// m97 structure: 128x128 tile, BK=32, global_load_lds width-16 into linear [128][32] LDS.
// OMODE: 0 = fp32 row-major, 1 = bf16 row-major, 2 = bf16 per-head transposed (for V)
template <int OMODE, bool RELU>
__global__ __launch_bounds__(256) void gemm_kernel(const unsigned short* __restrict__ A,
                                                   const unsigned short* __restrict__ WT,
                                                   const float* __restrict__ bias,
                                                   void* __restrict__ out,
                                                   int M, int N, int K) {
  __shared__ __align__(16) unsigned short sA[128 * 32];
  __shared__ __align__(16) unsigned short sB[128 * 32];
  int t = threadIdx.x;
  int w = t >> 6, l = t & 63;
  int ll = l & 15, lh = l >> 4;
  int bn = blockIdx.x, bm = blockIdx.y;
  int wm = (w & 1) * 64, wn = (w >> 1) * 64;

  f32x4 acc[4][4] = {};
  const size_t arow0 = (size_t)bm * 128;
  const size_t brow0 = (size_t)bn * 128;
  // staging coords: chunk c (1KB) -> rows c*16..c*16+15, lane covers (l>>2) row, (l&3)*8 col
  int c0 = w * 2;
  int r0 = c0 * 16 + (l >> 2), col0 = (l & 3) * 8;

  for (int kb = 0; kb < K; kb += 32) {
    __syncthreads();
    const unsigned short* gA = A + (arow0 + r0) * K + kb + col0;
    const unsigned short* gB = WT + (brow0 + r0) * K + kb + col0;
    gld16(sA + c0 * 512, gA, l);
    gld16(sA + c0 * 512 + 512, gA + (size_t)16 * K, l);
    gld16(sB + c0 * 512, gB, l);
    gld16(sB + c0 * 512 + 512, gB + (size_t)16 * K, l);
    __syncthreads();
    bf16x8 af[4], bfr[4];
#pragma unroll
    for (int mt = 0; mt < 4; ++mt)
      af[mt] = *(const bf16x8*)(sA + (wm + mt * 16 + ll) * 32 + lh * 8);
#pragma unroll
    for (int nt = 0; nt < 4; ++nt)
      bfr[nt] = *(const bf16x8*)(sB + (wn + nt * 16 + ll) * 32 + lh * 8);
#pragma unroll
    for (int mt = 0; mt < 4; ++mt)
#pragma unroll
      for (int nt = 0; nt < 4; ++nt)
        acc[mt][nt] = __builtin_amdgcn_mfma_f32_16x16x32_bf16(af[mt], bfr[nt], acc[mt][nt], 0, 0, 0);
  }

#pragma unroll
  for (int mt = 0; mt < 4; ++mt) {
#pragma unroll
    for (int nt = 0; nt < 4; ++nt) {
      int col = bn * 128 + wn + nt * 16 + ll;
      float bv = bias[col];
      if (OMODE == 2) {
        int row = bm * 128 + wm + mt * 16 + lh * 4;
        int b_ = row >> 11, s_ = row & 2047;
        size_t vr = ((size_t)(b_ * H + (col >> 6)) * 64 + (col & 63)) * S + s_;
        uint2 pk;
        pk.x = (unsigned)f2bf(acc[mt][nt][0] + bv) | ((unsigned)f2bf(acc[mt][nt][1] + bv) << 16);
        pk.y = (unsigned)f2bf(acc[mt][nt][2] + bv) | ((unsigned)f2bf(acc[mt][nt][3] + bv) << 16);
        *(uint2*)((unsigned short*)out + vr) = pk;
      } else {
#pragma unroll
        for (int r = 0; r < 4; ++r) {
          int row = bm * 128 + wm + mt * 16 + lh * 4 + r;
          float v = acc[mt][nt][r] + bv;
          if (RELU) v = fmaxf(v, 0.f);
          if (OMODE == 1)
            ((unsigned short*)out)[(size_t)row * N + col] = f2bf(v);
          else
            ((float*)out)[(size_t)row * N + col] = v;
        }
      }
    }
  }
}

// ---------------- Flash attention (swapped QK^T, barrier-free K-loop) ----------------
// Block: 4 waves x 32 q-rows = 128 q-rows. Each lane owns query q0+qs*16+ll.
// vt: per-head transposed V, [(b*H+h)*64 + d][s].
__global__ __launch_bounds__(256) void attn_kernel(const unsigned short* __restrict__ q,
                                                   const unsigned short* __restrict__ k,
                                                   const unsigned short* __restrict__ vt,
                                                   unsigned short* __restrict__ ctx) {
  __shared__ __align__(16) unsigned short sP[4][2][16 * 40];
  int t = threadIdx.x, w = t >> 6, l = t & 63;
  int ll = l & 15, lh = l >> 4;
  int bh = blockIdx.y;
  int q0 = blockIdx.x * 128 + w * 32;
  const size_t base = (size_t)(bh >> 4) * S * D + (size_t)(bh & 15) * DK;
  const size_t vtb = (size_t)bh * 64 * S;
  constexpr float SC = 0.125f;  // 1/sqrt(DK)

  bf16x8 qf[2][2];
#pragma unroll
  for (int qs = 0; qs < 2; ++qs)
#pragma unroll
    for (int kk = 0; kk < 2; ++kk)
      qf[qs][kk] = *(const bf16x8*)(q + base + (size_t)(q0 + qs * 16 + ll) * D + kk * 32 + lh * 8);

  f32x4 cacc[2][4] = {};
  float m[2] = {-1e30f, -1e30f}, lsum[2] = {0.f, 0.f};

  for (int kb = 0; kb < S; kb += 32) {
    bf16x8 kf[2][2];
#pragma unroll
    for (int nt = 0; nt < 2; ++nt)
#pragma unroll
      for (int kk = 0; kk < 2; ++kk)
        kf[nt][kk] = *(const bf16x8*)(k + base + (size_t)(kb + nt * 16 + ll) * D + kk * 32 + lh * 8);
    bf16x8 vf[4];
#pragma unroll
    for (int dt = 0; dt < 4; ++dt)
      vf[dt] = *(const bf16x8*)(vt + vtb + (size_t)(dt * 16 + ll) * S + kb + lh * 8);

#pragma unroll
    for (int qs = 0; qs < 2; ++qs) {
      f32x4 sc[2] = {};
#pragma unroll
      for (int nt = 0; nt < 2; ++nt) {
        sc[nt] = __builtin_amdgcn_mfma_f32_16x16x32_bf16(kf[nt][0], qf[qs][0], sc[nt], 0, 0, 0);
        sc[nt] = __builtin_amdgcn_mfma_f32_16x16x32_bf16(kf[nt][1], qf[qs][1], sc[nt], 0, 0, 0);
      }
      // lane holds S[key = nt*16+lh*4+r][query = ll]; reduce over keys
      float tm = fmaxf(fmaxf(sc[0][0], sc[0][1]), fmaxf(sc[0][2], sc[0][3]));
      tm = fmaxf(tm, fmaxf(fmaxf(sc[1][0], sc[1][1]), fmaxf(sc[1][2], sc[1][3])));
      tm = fmaxf(tm, __shfl_xor(tm, 16));
      tm = fmaxf(tm, __shfl_xor(tm, 32));
      float mn = fmaxf(m[qs], tm);
      float resc = __expf((m[qs] - mn) * SC);
      float p[2][4], ps = 0.f;
#pragma unroll
      for (int nt = 0; nt < 2; ++nt)
#pragma unroll
        for (int r = 0; r < 4; ++r) {
          p[nt][r] = __expf((sc[nt][r] - mn) * SC);
          ps += p[nt][r];
        }
      ps += __shfl_xor(ps, 16);
      ps += __shfl_xor(ps, 32);
      lsum[qs] = lsum[qs] * resc + ps;
      m[qs] = mn;
#pragma unroll
      for (int dt = 0; dt < 4; ++dt)
#pragma unroll
        for (int r = 0; r < 4; ++r) cacc[qs][dt][r] *= resc;
      // write P[q=ll][key 0..31] rows (stride 40 shorts), packed b64
#pragma unroll
      for (int nt = 0; nt < 2; ++nt) {
        uint2 pk;
        pk.x = (unsigned)f2bf(p[nt][0]) | ((unsigned)f2bf(p[nt][1]) << 16);
        pk.y = (unsigned)f2bf(p[nt][2]) | ((unsigned)f2bf(p[nt][3]) << 16);
        *(uint2*)(&sP[w][qs][ll * 40 + nt * 16 + lh * 4]) = pk;
      }
    }
#pragma unroll
    for (int qs = 0; qs < 2; ++qs) {
      bf16x8 pf = *(const bf16x8*)(&sP[w][qs][ll * 40 + lh * 8]);
#pragma unroll
      for (int dt = 0; dt < 4; ++dt)
        cacc[qs][dt] = __builtin_amdgcn_mfma_f32_16x16x32_bf16(pf, vf[dt], cacc[qs][dt], 0, 0, 0);
    }
  }

#pragma unroll
  for (int qs = 0; qs < 2; ++qs) {
    float inv[4];
#pragma unroll
    for (int r = 0; r < 4; ++r) inv[r] = 1.0f / __shfl(lsum[qs], lh * 4 + r);
#pragma unroll
    for (int dt = 0; dt < 4; ++dt)
#pragma unroll
      for (int r = 0; r < 4; ++r)
        ctx[base + (size_t)(q0 + qs * 16 + lh * 4 + r) * D + dt * 16 + ll] =
            f2bf(cacc[qs][dt][r] * inv[r]);
  }
}

// ---------------- residual + LayerNorm (fp32 out + optional bf16 out) ----------------
template <bool WRITE_BF16>
__global__ __launch_bounds__(256) void add_ln_kernel(const float* __restrict__ a,
                                                     const float* __restrict__ bres,
                                                     const float* __restrict__ gamma,
                                                     const float* __restrict__ beta,
                                                     float* __restrict__ outf,
                                                     unsigned short* __restrict__ outb) {
  __shared__ float sred[8];
  size_t row = blockIdx.x;
  int t = threadIdx.x;
  size_t bidx = row * D + t * 4;
  float4 va = *(const float4*)(a + bidx);
  float4 vb = *(const float4*)(bres + bidx);
  float4 x;
  x.x = va.x + vb.x; x.y = va.y + vb.y; x.z = va.z + vb.z; x.w = va.w + vb.w;

  float s = x.x + x.y + x.z + x.w;
#pragma unroll
  for (int msk = 32; msk; msk >>= 1) s += __shfl_xor(s, msk);
  if ((t & 63) == 0) sred[t >> 6] = s;
  __syncthreads();
  float mu = (sred[0] + sred[1] + sred[2] + sred[3]) * (1.f / D);

  float dx = x.x - mu, dy = x.y - mu, dz = x.z - mu, dw = x.w - mu;
  float sq = dx * dx + dy * dy + dz * dz + dw * dw;
#pragma unroll
  for (int msk = 32; msk; msk >>= 1) sq += __shfl_xor(sq, msk);
  __syncthreads();
  if ((t & 63) == 0) sred[t >> 6] = sq;
  __syncthreads();
  float var = (sred[0] + sred[1] + sred[2] + sred[3]) * (1.f / D);
  float rs = rsqrtf(var + 1e-5f);

  float4 g = *(const float4*)(gamma + t * 4);
  float4 be = *(const float4*)(beta + t * 4);
  float4 y;
  y.x = dx * rs * g.x + be.x;
  y.y = dy * rs * g.y + be.y;
  y.z = dz * rs * g.z + be.z;
  y.w = dw * rs * g.w + be.w;
  *(float4*)(outf + bidx) = y;
  if (WRITE_BF16) {
    uint2 o;
    o.x = (unsigned)f2bf(y.x) | ((unsigned)f2bf(y.y) << 16);
    o.y = (unsigned)f2bf(y.z) | ((unsigned)f2bf(y.w) << 16);
    *(uint2*)(outb + bidx) = o;
  }
}

extern "C" void kernel_launch(void* const* d_in, const int* in_sizes, int n_in,
                              void* d_out, int out_size, void* d_ws, size_t ws_size,
                              hipStream_t stream) {
  const float* x   = (const float*)d_in[0];
  const float* wq  = (const float*)d_in[1];
  const float* bq  = (const float*)d_in[2];
  const float* wk  = (const float*)d_in[3];
  const float* bk  = (const float*)d_in[4];
  const float* wv  = (const float*)d_in[5];
  const float* bv  = (const float*)d_in[6];
  const float* wo  = (const float*)d_in[7];
  const float* bo  = (const float*)d_in[8];
  const float* w1  = (const float*)d_in[9];
  const float* b1  = (const float*)d_in[10];
  const float* w2  = (const float*)d_in[11];
  const float* b2  = (const float*)d_in[12];
  const float* g1  = (const float*)d_in[13];
  const float* be1 = (const float*)d_in[14];
  const float* g2  = (const float*)d_in[15];
  const float* be2 = (const float*)d_in[16];

  char* ws = (char*)d_ws;
  size_t off = 0;
  auto alloc = [&](size_t bytes) {
    char* p = ws + off;
    off += (bytes + 255) & ~(size_t)255;
    return p;
  };

  unsigned short* wqT = (unsigned short*)alloc((size_t)D * D * 2);
  unsigned short* wkT = (unsigned short*)alloc((size_t)D * D * 2);
  unsigned short* wvT = (unsigned short*)alloc((size_t)D * D * 2);
  unsigned short* woT = (unsigned short*)alloc((size_t)D * D * 2);
  unsigned short* w1T = (unsigned short*)alloc((size_t)D * DFF * 2);
  unsigned short* w2T = (unsigned short*)alloc((size_t)DFF * D * 2);
  unsigned short* xb  = (unsigned short*)alloc((size_t)NT * D * 2);   // reused as x1b
  unsigned short* big = (unsigned short*)alloc((size_t)NT * DFF * 2); // q|k|ctx|vt, later ff
  unsigned short* qb  = big;
  unsigned short* kb_ = big + (size_t)NT * D;
  unsigned short* ctb = big + (size_t)2 * NT * D;
  unsigned short* vtb = big + (size_t)3 * NT * D;                     // per-head V^T (16 MiB)
  float* attn_out = (float*)alloc((size_t)NT * D * 4);                // reused as ff2
  float* x1f      = (float*)alloc((size_t)NT * D * 4);
  unsigned short* x1b = xb;
  unsigned short* ffb = big;
  float* ff2 = attn_out;
  (void)ws_size; (void)in_sizes; (void)n_in; (void)out_size;

  // 1. convert x + weights to bf16 (weights transposed)
  cvt_bf16_kernel<<<NT * D / 2048, 256, 0, stream>>>(x, xb, NT * D);
  transpose_cvt_kernel<<<dim3(D / 64, D / 64), 256, 0, stream>>>(wq, wqT, D, D);
  transpose_cvt_kernel<<<dim3(D / 64, D / 64), 256, 0, stream>>>(wk, wkT, D, D);
  transpose_cvt_kernel<<<dim3(D / 64, D / 64), 256, 0, stream>>>(wv, wvT, D, D);
  transpose_cvt_kernel<<<dim3(D / 64, D / 64), 256, 0, stream>>>(wo, woT, D, D);
  transpose_cvt_kernel<<<dim3(DFF / 64, D / 64), 256, 0, stream>>>(w1, w1T, D, DFF);
  transpose_cvt_kernel<<<dim3(D / 64, DFF / 64), 256, 0, stream>>>(w2, w2T, DFF, D);

  // 2. QKV projections (V written per-head transposed)
  gemm_kernel<1, false><<<dim3(D / 128, NT / 128), 256, 0, stream>>>(xb, wqT, bq, qb, NT, D, D);
  gemm_kernel<1, false><<<dim3(D / 128, NT / 128), 256, 0, stream>>>(xb, wkT, bk, kb_, NT, D, D);
  gemm_kernel<2, false><<<dim3(D / 128, NT / 128), 256, 0, stream>>>(xb, wvT, bv, vtb, NT, D, D);

  // 3. attention
  attn_kernel<<<dim3(S / 128, B * H), 256, 0, stream>>>(qb, kb_, vtb, ctb);

  // 4. output projection (fp32 out for residual)
  gemm_kernel<0, false><<<dim3(D / 128, NT / 128), 256, 0, stream>>>(ctb, woT, bo, attn_out, NT, D, D);

  // 5. x1 = LN(x + attn_out)
  add_ln_kernel<true><<<NT, 256, 0, stream>>>(x, attn_out, g1, be1, x1f, x1b);

  // 6. FF
  gemm_kernel<1, true><<<dim3(DFF / 128, NT / 128), 256, 0, stream>>>(x1b, w1T, b1, ffb, NT, DFF, D);
  gemm_kernel<0, false><<<dim3(D / 128, NT / 128), 256, 0, stream>>>(ffb, w2T, b2, ff2, NT, D, DFF);

  // 7. out = LN(x1 + ff)
  add_ln_kernel<false><<<NT, 256, 0, stream>>>(x1f, ff2, g2, be2, (float*)d_out, nullptr);
}